// Round 2
// baseline (1238.434 us; speedup 1.0000x reference)
//
#include <hip/hip_runtime.h>
#include <hip/hip_bf16.h>

#define BB 16
#define LL 2048
#define DD 512
#define HH 1024
#define NL 4
#define MM (BB*LL)   // 32768

typedef __attribute__((ext_vector_type(8))) short bh8;
typedef __attribute__((ext_vector_type(4))) float f4;

__device__ __forceinline__ unsigned short f2bf(float f) {
    unsigned int u = __float_as_uint(f);
    unsigned int r = (u + 0x7FFFu + ((u >> 16) & 1u)) >> 16;
    return (unsigned short)r;
}
__device__ __forceinline__ float bf2f(unsigned short u) {
    return __uint_as_float(((unsigned int)u) << 16);
}

// ---------------- FREQS_CIS table [L, D]: d<256 -> cos(l*f_d), d>=256 -> sin(l*f_{d-256})
__global__ __launch_bounds__(256) void freqs_kernel(float* __restrict__ fr) {
    int idx = blockIdx.x * 256 + threadIdx.x;     // over L*256 pairs
    int l = idx >> 8;
    int j = idx & 255;
    // f_j = 10000^(-j/256) = exp(-j * ln(10000)/256); ln(10000)/256 = 0.03597789207803196381
    double f = exp(-(double)j * 0.03597789207803196381);
    double a = (double)l * f;
    fr[(size_t)l * DD + j]        = (float)cos(a);
    fr[(size_t)l * DD + 256 + j]  = (float)sin(a);
}

// ---------------- weight transpose+convert: in [NL][R][C] f32 -> out [NL][C][R] bf16
__global__ __launch_bounds__(256) void wtrans_kernel(const float* __restrict__ w,
                                                     unsigned short* __restrict__ wt,
                                                     int R, int C) {
    size_t idx = (size_t)blockIdx.x * 256 + threadIdx.x;  // over NL*R*C
    size_t per = (size_t)R * C;
    int layer = (int)(idx / per);
    int rr = (int)(idx % per);
    int ir = rr % R;          // output col = input row
    int oc = rr / R;          // output row = input col
    float v = w[(size_t)layer * per + (size_t)ir * C + oc];
    wt[idx] = f2bf(v);
}

// ---------------- embedding + freqs + mask
__global__ __launch_bounds__(512) void embed_kernel(const int* __restrict__ text,
                                                    const float* __restrict__ table,
                                                    const float* __restrict__ fr,
                                                    float* __restrict__ x) {
    int bid = blockIdx.x;            // b*L + l
    int d = threadIdx.x;
    int l = bid & (LL - 1);
    int t = text[bid] + 1;
    float v = 0.0f;
    if (t != 0) v = table[(size_t)t * DD + d] + fr[(size_t)l * DD + d];
    x[(size_t)bid * DD + d] = v;
}

// ---------------- depthwise conv7 (pad 3) + bias + LayerNorm -> bf16
__global__ __launch_bounds__(512) void conv_ln_kernel(const float* __restrict__ x,
                                                      const float* __restrict__ dw_w,
                                                      const float* __restrict__ dw_b,
                                                      const float* __restrict__ ln_g,
                                                      const float* __restrict__ ln_b,
                                                      unsigned short* __restrict__ xln) {
    int bid = blockIdx.x;            // b*L + l
    int l = bid & (LL - 1);
    int d = threadIdx.x;
    size_t rowbase = (size_t)bid * DD;

    float wreg[7];
    const float* wp = dw_w + (size_t)d * 7;
    #pragma unroll
    for (int k = 0; k < 7; k++) wreg[k] = wp[k];

    float acc = dw_b[d];
    const float* xc = x + rowbase + d;
    #pragma unroll
    for (int k = 0; k < 7; k++) {
        int ll = l + k - 3;
        if (ll >= 0 && ll < LL) acc += wreg[k] * xc[(ptrdiff_t)(k - 3) * DD];
    }

    // block reduction over 512 threads (8 waves)
    float s1 = acc, s2 = acc * acc;
    #pragma unroll
    for (int off = 32; off > 0; off >>= 1) {
        s1 += __shfl_down(s1, off);
        s2 += __shfl_down(s2, off);
    }
    __shared__ float r1[8], r2[8];
    int wid = d >> 6;
    if ((d & 63) == 0) { r1[wid] = s1; r2[wid] = s2; }
    __syncthreads();
    float t1 = 0.f, t2 = 0.f;
    #pragma unroll
    for (int i = 0; i < 8; i++) { t1 += r1[i]; t2 += r2[i]; }
    float mu = t1 * (1.0f / DD);
    float var = t2 * (1.0f / DD) - mu * mu;
    float v = (acc - mu) * rsqrtf(var + 1e-6f) * ln_g[d] + ln_b[d];
    xln[rowbase + d] = f2bf(v);
}

// ---------------- bf16 MFMA GEMM: C[m,n] = sum_k A[m,k] * Bt[n,k]
// MODE 0: h = bf16(gelu(C + bias))      (NDIM = H)
// MODE 1: x = mask ? 0 : (x + C + bias) (NDIM = D)
template<int KDIM, int NDIM, int MODE>
__global__ __launch_bounds__(256) void gemm_bf16_kernel(const unsigned short* __restrict__ A,
                                                        const unsigned short* __restrict__ Bt,
                                                        const float* __restrict__ bias,
                                                        unsigned short* __restrict__ hout,
                                                        float* __restrict__ xio,
                                                        const int* __restrict__ text) {
    __shared__ unsigned short lsA[128 * 40];
    __shared__ unsigned short lsB[128 * 40];
    const int t = threadIdx.x;
    const int m0 = blockIdx.y * 128;
    const int n0 = blockIdx.x * 128;
    const int lane = t & 63, wv = t >> 6;
    const int wr = wv >> 1, wc = wv & 1;
    const int rA = wr * 64 + (lane & 15);
    const int rB = wc * 64 + (lane & 15);
    const int kc = (lane >> 4) * 8;

    const f4 vzero = {0.f, 0.f, 0.f, 0.f};
    f4 acc[4][4];
    #pragma unroll
    for (int i = 0; i < 4; i++)
        #pragma unroll
        for (int j = 0; j < 4; j++) acc[i][j] = vzero;

    const int r0 = t >> 2, c0 = t & 3;

    for (int kt = 0; kt < KDIM / 32; kt++) {
        __syncthreads();
        #pragma unroll
        for (int s = 0; s < 2; s++) {
            int row = r0 + s * 64;
            bh8 va = *(const bh8*)(A  + (size_t)(m0 + row) * KDIM + kt * 32 + c0 * 8);
            bh8 vb = *(const bh8*)(Bt + (size_t)(n0 + row) * KDIM + kt * 32 + c0 * 8);
            *(bh8*)&lsA[row * 40 + c0 * 8] = va;
            *(bh8*)&lsB[row * 40 + c0 * 8] = vb;
        }
        __syncthreads();
        bh8 af[4], bfr[4];
        #pragma unroll
        for (int i = 0; i < 4; i++) af[i]  = *(bh8*)&lsA[(rA + i * 16) * 40 + kc];
        #pragma unroll
        for (int j = 0; j < 4; j++) bfr[j] = *(bh8*)&lsB[(rB + j * 16) * 40 + kc];
        #pragma unroll
        for (int i = 0; i < 4; i++)
            #pragma unroll
            for (int j = 0; j < 4; j++)
                acc[i][j] = __builtin_amdgcn_mfma_f32_16x16x32_bf16(af[i], bfr[j], acc[i][j], 0, 0, 0);
    }

    const int rowOff = (lane >> 4) * 4;
    const int colOff = lane & 15;
    #pragma unroll
    for (int i = 0; i < 4; i++) {
        #pragma unroll
        for (int j = 0; j < 4; j++) {
            int n = n0 + wc * 64 + j * 16 + colOff;
            float bn = bias[n];
            #pragma unroll
            for (int r = 0; r < 4; r++) {
                int m = m0 + wr * 64 + i * 16 + rowOff + r;
                float v = acc[i][j][r] + bn;
                if constexpr (MODE == 0) {
                    v = 0.5f * v * (1.0f + erff(v * 0.70710678118654752f));
                    hout[(size_t)m * NDIM + n] = f2bf(v);
                } else {
                    size_t o = (size_t)m * NDIM + n;
                    v += xio[o];
                    if (text[m] == -1) v = 0.0f;
                    xio[o] = v;
                }
            }
        }
    }
}

// ---------------- GRN partial square-sums: gxp[lc][b][ch] = sum over 256 l of h^2
__global__ __launch_bounds__(256) void grn_sq_kernel(const unsigned short* __restrict__ h,
                                                     float* __restrict__ gxp) {
    int bid = blockIdx.x;                 // 16*4*8 = 512 blocks
    int lc = bid & 7;
    int ct = (bid >> 3) & 3;
    int b  = bid >> 5;
    int ch = ct * 256 + threadIdx.x;
    float s = 0.f;
    size_t base = ((size_t)b * LL + (size_t)lc * 256) * HH + ch;
    for (int i = 0; i < 256; i++) {
        float v = bf2f(h[base + (size_t)i * HH]);
        s += v * v;
    }
    gxp[((size_t)lc * BB + b) * HH + ch] = s;
}

// ---------------- GRN stats: Nx[b,ch] = sqrt(S)/ (mean_ch sqrt(S) + 1e-6)
__global__ __launch_bounds__(256) void grn_stats_kernel(const float* __restrict__ gxp,
                                                        float* __restrict__ nx) {
    int b = blockIdx.x, t = threadIdx.x;
    float g[4];
    float s = 0.f;
    #pragma unroll
    for (int e = 0; e < 4; e++) {
        int ch = t + e * 256;
        float acc = 0.f;
        #pragma unroll
        for (int lc = 0; lc < 8; lc++) acc += gxp[((size_t)lc * BB + b) * HH + ch];
        g[e] = sqrtf(acc);
        s += g[e];
    }
    #pragma unroll
    for (int off = 32; off > 0; off >>= 1) s += __shfl_down(s, off);
    __shared__ float rs[4];
    if ((t & 63) == 0) rs[t >> 6] = s;
    __syncthreads();
    float tot = rs[0] + rs[1] + rs[2] + rs[3];
    float mean = tot * (1.0f / HH);
    float inv = 1.0f / (mean + 1e-6f);
    #pragma unroll
    for (int e = 0; e < 4; e++) nx[(size_t)b * HH + t + e * 256] = g[e] * inv;
}

// ---------------- GRN apply (in place on h): h = bf16(gg*(h*Nx) + gb + h)
__global__ __launch_bounds__(256) void grn_apply_kernel(unsigned short* __restrict__ h,
                                                        const float* __restrict__ nx,
                                                        const float* __restrict__ gg,
                                                        const float* __restrict__ gb) {
    size_t idx = (size_t)blockIdx.x * 256 + threadIdx.x;   // M*H/8 threads
    size_t flat = idx * 8;
    int ch = (int)(flat & (HH - 1));
    int b = (int)(flat / ((size_t)LL * HH));
    bh8 v = *(bh8*)(h + flat);
    bh8 o;
    #pragma unroll
    for (int e = 0; e < 8; e++) {
        float f = bf2f((unsigned short)v[e]);
        float nv = nx[(size_t)b * HH + ch + e];
        float r = gg[ch + e] * (f * nv) + gb[ch + e] + f;
        o[e] = (short)f2bf(r);
    }
    *(bh8*)(h + flat) = o;
}

// ---------------- upsample scan: pos (compacted valid positions), lens
__global__ __launch_bounds__(256) void upscan_kernel(const int* __restrict__ text,
                                                     const int* __restrict__ audio,
                                                     int* __restrict__ pos,
                                                     int* __restrict__ lens) {
    int b = blockIdx.x, t = threadIdx.x;
    __shared__ int sc[256];
    int voff = 0, aoff = 0;
    for (int c = 0; c < LL / 256; c++) {
        int l = c * 256 + t;
        int am = audio[(size_t)b * LL + l];
        int tv = text[(size_t)b * LL + l];
        int valid = (am != 0 && tv != -1) ? 1 : 0;
        sc[t] = valid;
        __syncthreads();
        for (int off = 1; off < 256; off <<= 1) {
            int add = (t >= off) ? sc[t - off] : 0;
            __syncthreads();
            sc[t] += add;
            __syncthreads();
        }
        int incl = sc[t];
        if (valid) pos[(size_t)b * LL + voff + incl - 1] = l;
        voff += sc[255];
        __syncthreads();
        sc[t] = (am != 0) ? 1 : 0;
        __syncthreads();
        for (int off = 128; off > 0; off >>= 1) {
            if (t < off) sc[t] += sc[t + off];
            __syncthreads();
        }
        aoff += sc[0];
        __syncthreads();
    }
    if (t == 0) { lens[b * 2] = aoff; lens[b * 2 + 1] = voff; }
    for (int i = voff + t; i < LL; i += 256) pos[(size_t)b * LL + i] = LL - 1;
}

// ---------------- upsample gather
__global__ __launch_bounds__(256) void upgather_kernel(const float* __restrict__ x,
                                                       const int* __restrict__ pos,
                                                       const int* __restrict__ lens,
                                                       float* __restrict__ out) {
    int bid = blockIdx.x;            // b*L + p
    int b = bid >> 11;
    int p = bid & (LL - 1);
    int t = threadIdx.x;
    int alen = lens[b * 2], vlen = lens[b * 2 + 1];
    float v0 = 0.f, v1 = 0.f;
    if (p < alen && vlen > 0) {
        int vl = vlen < 1 ? 1 : vlen;
        int base = alen / vl, rem = alen % vl;
        int cut = (vl - rem) * base;
        int j;
        if (p < cut) j = p / (base < 1 ? 1 : base);
        else j = (vl - rem) + (p - cut) / (base + 1);
        j = j < 0 ? 0 : (j > LL - 1 ? LL - 1 : j);
        int s = pos[(size_t)b * LL + j];
        s = s < 0 ? 0 : (s > LL - 1 ? LL - 1 : s);
        const float* xr = x + ((size_t)b * LL + s) * DD;
        v0 = xr[t];
        v1 = xr[t + 256];
    }
    out[(size_t)bid * DD + t] = v0;
    out[(size_t)bid * DD + t + 256] = v1;
}

// ---------------- workspace layout (bytes)
#define OFF_FREQS  ((size_t)0)
#define OFF_X      (OFF_FREQS + (size_t)LL * DD * 4)          // 4 MB
#define OFF_XLN    (OFF_X + (size_t)MM * DD * 4)              // +64 MB
#define OFF_H      (OFF_XLN + (size_t)MM * DD * 2)            // +32 MB
#define OFF_W1T    (OFF_H + (size_t)MM * HH * 2)              // +64 MB
#define OFF_W2T    (OFF_W1T + (size_t)NL * HH * DD * 2)       // +4 MB
#define OFF_GXP    (OFF_W2T + (size_t)NL * DD * HH * 2)       // +4 MB
#define OFF_NX     (OFF_GXP + (size_t)8 * BB * HH * 4)        // +512 KB
#define OFF_POS    (OFF_NX + (size_t)BB * HH * 4)             // +64 KB
#define OFF_LENS   (OFF_POS + (size_t)BB * LL * 4)            // +128 KB

extern "C" void kernel_launch(void* const* d_in, const int* in_sizes, int n_in,
                              void* d_out, int out_size, void* d_ws, size_t ws_size,
                              hipStream_t stream) {
    const int*   text  = (const int*)d_in[0];
    const int*   audio = (const int*)d_in[1];
    const float* table = (const float*)d_in[3];
    const float* dw_w  = (const float*)d_in[4];
    const float* dw_b  = (const float*)d_in[5];
    const float* ln_g  = (const float*)d_in[6];
    const float* ln_b  = (const float*)d_in[7];
    const float* pw1_w = (const float*)d_in[8];
    const float* pw1_b = (const float*)d_in[9];
    const float* grn_g = (const float*)d_in[10];
    const float* grn_b = (const float*)d_in[11];
    const float* pw2_w = (const float*)d_in[12];
    const float* pw2_b = (const float*)d_in[13];
    float* out = (float*)d_out;

    char* ws = (char*)d_ws;
    float*          freqs = (float*)(ws + OFF_FREQS);
    float*          x     = (float*)(ws + OFF_X);
    unsigned short* xln   = (unsigned short*)(ws + OFF_XLN);
    unsigned short* h     = (unsigned short*)(ws + OFF_H);
    unsigned short* w1t   = (unsigned short*)(ws + OFF_W1T);
    unsigned short* w2t   = (unsigned short*)(ws + OFF_W2T);
    float*          gxp   = (float*)(ws + OFF_GXP);
    float*          nx    = (float*)(ws + OFF_NX);
    int*            pos   = (int*)(ws + OFF_POS);
    int*            lens  = (int*)(ws + OFF_LENS);

    freqs_kernel<<<LL * 256 / 256, 256, 0, stream>>>(freqs);
    wtrans_kernel<<<NL * DD * HH / 256, 256, 0, stream>>>(pw1_w, w1t, DD, HH);
    wtrans_kernel<<<NL * DD * HH / 256, 256, 0, stream>>>(pw2_w, w2t, HH, DD);
    embed_kernel<<<MM, 512, 0, stream>>>(text, table, freqs, x);

    for (int layer = 0; layer < NL; layer++) {
        conv_ln_kernel<<<MM, 512, 0, stream>>>(x,
            dw_w + (size_t)layer * DD * 7, dw_b + (size_t)layer * DD,
            ln_g + (size_t)layer * DD, ln_b + (size_t)layer * DD, xln);

        gemm_bf16_kernel<DD, HH, 0><<<dim3(HH / 128, MM / 128), 256, 0, stream>>>(
            xln, w1t + (size_t)layer * HH * DD, pw1_b + (size_t)layer * HH,
            h, nullptr, nullptr);

        grn_sq_kernel<<<BB * (HH / 256) * (LL / 256), 256, 0, stream>>>(h, gxp);
        grn_stats_kernel<<<BB, 256, 0, stream>>>(gxp, nx);
        grn_apply_kernel<<<(int)(((size_t)MM * HH / 8) / 256), 256, 0, stream>>>(
            h, nx, grn_g + (size_t)layer * HH, grn_b + (size_t)layer * HH);

        gemm_bf16_kernel<HH, DD, 1><<<dim3(DD / 128, MM / 128), 256, 0, stream>>>(
            h, w2t + (size_t)layer * DD * HH, pw2_b + (size_t)layer * DD,
            nullptr, x, text);
    }

    upscan_kernel<<<BB, 256, 0, stream>>>(text, audio, pos, lens);
    upgather_kernel<<<MM, 256, 0, stream>>>(x, pos, lens, out);
}

// Round 3
// 727.053 us; speedup vs baseline: 1.7034x; 1.7034x over previous
//
#include <hip/hip_runtime.h>
#include <hip/hip_bf16.h>

#define BB 16
#define LL 2048
#define DD 512
#define HH 1024
#define NL 4
#define MM (BB*LL)   // 32768

typedef __attribute__((ext_vector_type(8))) short bh8;
typedef __attribute__((ext_vector_type(4))) float f4;

typedef __attribute__((address_space(3))) unsigned int lds_u32;
typedef __attribute__((address_space(1))) const unsigned int glob_u32;

__device__ __forceinline__ void gld_lds16(const void* g, void* l) {
    __builtin_amdgcn_global_load_lds((glob_u32*)g, (lds_u32*)l, 16, 0, 0);
}

__device__ __forceinline__ unsigned short f2bf(float f) {
    unsigned int u = __float_as_uint(f);
    unsigned int r = (u + 0x7FFFu + ((u >> 16) & 1u)) >> 16;
    return (unsigned short)r;
}
__device__ __forceinline__ float bf2f(unsigned short u) {
    return __uint_as_float(((unsigned int)u) << 16);
}

// fast GELU (tanh form, abs err ~1e-4 vs exact erf — far below 4.6e-2 threshold)
__device__ __forceinline__ float gelu_f(float v) {
    float y = 0.7978845608028654f * v * fmaf(0.044715f, v * v, 1.0f);
    float e = __expf(2.0f * y);
    float th = 1.0f - 2.0f * __builtin_amdgcn_rcpf(e + 1.0f);
    return 0.5f * v * (1.0f + th);
}

// ---------------- FREQS_CIS table [L, D] (f32 math; phase err <2e-4 rad)
__global__ __launch_bounds__(256) void freqs_kernel(float* __restrict__ fr) {
    int idx = blockIdx.x * 256 + threadIdx.x;     // over L*256 pairs
    int l = idx >> 8;
    int j = idx & 255;
    float f = exp2f(-(float)j * 0.051905126482615036f);  // log2(10000)/256
    float a = (float)l * f;
    fr[(size_t)l * DD + j]       = cosf(a);
    fr[(size_t)l * DD + 256 + j] = sinf(a);
}

// ---------------- weight transpose+convert: [NL][R][C] f32 -> [NL][C][R] bf16 (64x64 LDS tiles)
__global__ __launch_bounds__(256) void wtrans_kernel(const float* __restrict__ w,
                                                     unsigned short* __restrict__ wt,
                                                     int R, int C) {
    __shared__ float ls[64][65];
    int layer = blockIdx.z;
    int tr = blockIdx.y;     // row tile of input
    int tc = blockIdx.x;     // col tile of input
    const float* src = w + (size_t)layer * R * C + (size_t)(tr * 64) * C + tc * 64;
    int t = threadIdx.x;
    #pragma unroll
    for (int s = 0; s < 4; s++) {
        int r = (t >> 4) + 16 * s, c = (t & 15) * 4;
        f4 v = *(const f4*)(src + (size_t)r * C + c);
        ls[r][c] = v.x; ls[r][c + 1] = v.y; ls[r][c + 2] = v.z; ls[r][c + 3] = v.w;
    }
    __syncthreads();
    unsigned short* dst = wt + (size_t)layer * R * C + (size_t)(tc * 64) * R + tr * 64;
    #pragma unroll
    for (int s = 0; s < 2; s++) {
        int idx = t + 256 * s;        // 0..511
        int c = idx >> 3;             // 0..63 output row
        int r8 = (idx & 7) * 8;
        bh8 o;
        #pragma unroll
        for (int e = 0; e < 8; e++) o[e] = (short)f2bf(ls[r8 + e][c]);
        *(bh8*)(dst + (size_t)c * R + r8) = o;
    }
}

// ---------------- embedding + freqs + mask (float4)
__global__ __launch_bounds__(128) void embed_kernel(const int* __restrict__ text,
                                                    const float* __restrict__ table,
                                                    const float* __restrict__ fr,
                                                    float* __restrict__ x) {
    int bid = blockIdx.x;            // b*L + l
    int d4 = threadIdx.x;            // 128 float4 lanes
    int l = bid & (LL - 1);
    int tok = text[bid] + 1;
    f4 v = {0.f, 0.f, 0.f, 0.f};
    if (tok != 0) {
        f4 e = *(const f4*)(table + (size_t)tok * DD + d4 * 4);
        f4 f = *(const f4*)(fr + (size_t)l * DD + d4 * 4);
        v.x = e.x + f.x; v.y = e.y + f.y; v.z = e.z + f.z; v.w = e.w + f.w;
    }
    *(f4*)(x + (size_t)bid * DD + d4 * 4) = v;
}

// ---------------- depthwise conv7 + bias + LayerNorm -> bf16
// wave owns 16 consecutive rows; thread owns 8 channels; ring buffer of 8 rows; no __syncthreads
#define CCH 16
__global__ __launch_bounds__(256) void conv_ln_kernel(const float* __restrict__ x,
                                                      const float* __restrict__ dw_w,
                                                      const float* __restrict__ dw_b,
                                                      const float* __restrict__ ln_g,
                                                      const float* __restrict__ ln_b,
                                                      unsigned short* __restrict__ xln) {
    const int t = threadIdx.x;
    const int lane = t & 63, wv = t >> 6;
    const int chunk = blockIdx.x * 4 + wv;       // 2048 chunks
    const int row0 = chunk * CCH;                // global row = b*L + l
    const int l0 = row0 & (LL - 1);
    const int d0 = lane * 8;
    const float* xb = x + ((size_t)(row0 >> 11) * LL) * DD + d0;   // + l*DD for row l

    float w[7][8], cb[8], g[8], be[8];
    #pragma unroll
    for (int e = 0; e < 8; e++) {
        #pragma unroll
        for (int k = 0; k < 7; k++) w[k][e] = dw_w[(d0 + e) * 7 + k];
        cb[e] = dw_b[d0 + e];
        g[e]  = ln_g[d0 + e];
        be[e] = ln_b[d0 + e];
    }

    float ring[8][8];
    #pragma unroll
    for (int ii = 0; ii < 8; ii++) {
        int i = ii - 3;                       // input rows l0-3 .. l0+4
        int s = i & 7;
        int l = l0 + i;
        bool ok = (unsigned)l < LL;
        f4 v0 = {0,0,0,0}, v1 = {0,0,0,0};
        if (ok) {
            const f4* p = (const f4*)(xb + (size_t)l * DD);
            v0 = p[0]; v1 = p[1];
        }
        ring[s][0]=v0.x; ring[s][1]=v0.y; ring[s][2]=v0.z; ring[s][3]=v0.w;
        ring[s][4]=v1.x; ring[s][5]=v1.y; ring[s][6]=v1.z; ring[s][7]=v1.w;
    }

    #pragma unroll
    for (int r = 0; r < CCH; r++) {
        float acc[8];
        #pragma unroll
        for (int e = 0; e < 8; e++) acc[e] = cb[e];
        #pragma unroll
        for (int k = 0; k < 7; k++) {
            int s = (r + k - 3) & 7;
            #pragma unroll
            for (int e = 0; e < 8; e++) acc[e] = fmaf(w[k][e], ring[s][e], acc[e]);
        }
        // prefetch input row r+5 into the just-freed slot
        {
            int s = (r + 5) & 7;
            int l = l0 + r + 5;
            bool ok = (unsigned)l < LL;
            f4 v0 = {0,0,0,0}, v1 = {0,0,0,0};
            if (ok) {
                const f4* p = (const f4*)(xb + (size_t)l * DD);
                v0 = p[0]; v1 = p[1];
            }
            ring[s][0]=v0.x; ring[s][1]=v0.y; ring[s][2]=v0.z; ring[s][3]=v0.w;
            ring[s][4]=v1.x; ring[s][5]=v1.y; ring[s][6]=v1.z; ring[s][7]=v1.w;
        }
        float s1 = 0.f, s2 = 0.f;
        #pragma unroll
        for (int e = 0; e < 8; e++) { s1 += acc[e]; s2 = fmaf(acc[e], acc[e], s2); }
        #pragma unroll
        for (int off = 1; off <= 32; off <<= 1) {
            s1 += __shfl_xor(s1, off, 64);
            s2 += __shfl_xor(s2, off, 64);
        }
        float mu = s1 * (1.0f / DD);
        float var = s2 * (1.0f / DD) - mu * mu;
        float rstd = rsqrtf(var + 1e-6f);
        bh8 o;
        #pragma unroll
        for (int e = 0; e < 8; e++) o[e] = (short)f2bf((acc[e] - mu) * rstd * g[e] + be[e]);
        *(bh8*)(xln + (size_t)(row0 + r) * DD + d0) = o;
    }
}

// ---------------- bf16 MFMA GEMM (m97 structure: global_load_lds w16, linear LDS, XCD swizzle)
// MODE 0: h = bf16(gelu(C + bias));  MODE 1: x = mask ? 0 : (x + C + bias)
template<int KDIM, int NDIM, int MODE>
__global__ __launch_bounds__(256) void gemm_bf16_kernel(const unsigned short* __restrict__ A,
                                                        const unsigned short* __restrict__ Bt,
                                                        const float* __restrict__ bias,
                                                        unsigned short* __restrict__ hout,
                                                        float* __restrict__ xio,
                                                        const int* __restrict__ text) {
    __shared__ unsigned short lsA[128 * 32];
    __shared__ unsigned short lsB[128 * 32];
    const int t = threadIdx.x;
    constexpr int NX = NDIM / 128;
    constexpr int NWG = NX * (MM / 128);
    const int id = blockIdx.y * NX + blockIdx.x;
    const int sw = (id & 7) * (NWG / 8) + (id >> 3);     // XCD-chunked (NWG%8==0)
    const int m0 = (sw / NX) * 128;
    const int n0 = (sw % NX) * 128;

    const int lane = t & 63, wv = t >> 6;
    const int wr = wv >> 1, wc = wv & 1;
    const int rA = wr * 64 + (lane & 15);
    const int rB = wc * 64 + (lane & 15);
    const int kc = (lane >> 4) * 8;
    const int srow = t >> 2, scol = (t & 3) * 8;         // staging: lds byte = t*16 (+ s*4096)

    const f4 vzero = {0.f, 0.f, 0.f, 0.f};
    f4 acc[4][4];
    #pragma unroll
    for (int i = 0; i < 4; i++)
        #pragma unroll
        for (int j = 0; j < 4; j++) acc[i][j] = vzero;

    const unsigned short* Ab = A + (size_t)m0 * KDIM;
    const unsigned short* Bb = Bt + (size_t)n0 * KDIM;

    for (int kt = 0; kt < KDIM / 32; kt++) {
        __syncthreads();
        const int ko = kt * 32 + scol;
        gld_lds16(Ab + (size_t)srow * KDIM + ko,        &lsA[srow * 32 + scol]);
        gld_lds16(Ab + (size_t)(srow + 64) * KDIM + ko, &lsA[(srow + 64) * 32 + scol]);
        gld_lds16(Bb + (size_t)srow * KDIM + ko,        &lsB[srow * 32 + scol]);
        gld_lds16(Bb + (size_t)(srow + 64) * KDIM + ko, &lsB[(srow + 64) * 32 + scol]);
        __syncthreads();
        bh8 af[4], bfv[4];
        #pragma unroll
        for (int i = 0; i < 4; i++) af[i]  = *(bh8*)&lsA[(rA + i * 16) * 32 + kc];
        #pragma unroll
        for (int j = 0; j < 4; j++) bfv[j] = *(bh8*)&lsB[(rB + j * 16) * 32 + kc];
        #pragma unroll
        for (int i = 0; i < 4; i++)
            #pragma unroll
            for (int j = 0; j < 4; j++)
                acc[i][j] = __builtin_amdgcn_mfma_f32_16x16x32_bf16(af[i], bfv[j], acc[i][j], 0, 0, 0);
    }

    const int rowOff = (lane >> 4) * 4;
    const int colOff = lane & 15;
    #pragma unroll
    for (int i = 0; i < 4; i++) {
        #pragma unroll
        for (int j = 0; j < 4; j++) {
            int n = n0 + wc * 64 + j * 16 + colOff;
            float bn = bias[n];
            #pragma unroll
            for (int r = 0; r < 4; r++) {
                int m = m0 + wr * 64 + i * 16 + rowOff + r;
                float v = acc[i][j][r] + bn;
                if constexpr (MODE == 0) {
                    hout[(size_t)m * NDIM + n] = f2bf(gelu_f(v));
                } else {
                    size_t o = (size_t)m * NDIM + n;
                    v += xio[o];
                    if (text[m] == -1) v = 0.0f;
                    xio[o] = v;
                }
            }
        }
    }
}

// ---------------- GRN partial square-sums
__global__ __launch_bounds__(256) void grn_sq_kernel(const unsigned short* __restrict__ h,
                                                     float* __restrict__ gxp) {
    int bid = blockIdx.x;                 // 512 blocks
    int lc = bid & 7;
    int ct = (bid >> 3) & 3;
    int b  = bid >> 5;
    int ch = ct * 256 + threadIdx.x;
    float s = 0.f;
    size_t base = ((size_t)b * LL + (size_t)lc * 256) * HH + ch;
    for (int i = 0; i < 256; i++) {
        float v = bf2f(h[base + (size_t)i * HH]);
        s += v * v;
    }
    gxp[((size_t)lc * BB + b) * HH + ch] = s;
}

// ---------------- GRN stats
__global__ __launch_bounds__(256) void grn_stats_kernel(const float* __restrict__ gxp,
                                                        float* __restrict__ nx) {
    int b = blockIdx.x, t = threadIdx.x;
    float g[4];
    float s = 0.f;
    #pragma unroll
    for (int e = 0; e < 4; e++) {
        int ch = t + e * 256;
        float acc = 0.f;
        #pragma unroll
        for (int lc = 0; lc < 8; lc++) acc += gxp[((size_t)lc * BB + b) * HH + ch];
        g[e] = sqrtf(acc);
        s += g[e];
    }
    #pragma unroll
    for (int off = 32; off > 0; off >>= 1) s += __shfl_down(s, off);
    __shared__ float rs[4];
    if ((t & 63) == 0) rs[t >> 6] = s;
    __syncthreads();
    float tot = rs[0] + rs[1] + rs[2] + rs[3];
    float mean = tot * (1.0f / HH);
    float inv = 1.0f / (mean + 1e-6f);
    #pragma unroll
    for (int e = 0; e < 4; e++) nx[(size_t)b * HH + t + e * 256] = g[e] * inv;
}

// ---------------- GRN apply (in place on h)
__global__ __launch_bounds__(256) void grn_apply_kernel(unsigned short* __restrict__ h,
                                                        const float* __restrict__ nx,
                                                        const float* __restrict__ gg,
                                                        const float* __restrict__ gb) {
    size_t idx = (size_t)blockIdx.x * 256 + threadIdx.x;
    size_t flat = idx * 8;
    int ch = (int)(flat & (HH - 1));
    int b = (int)(flat / ((size_t)LL * HH));
    bh8 v = *(bh8*)(h + flat);
    f4 n0 = *(const f4*)(nx + (size_t)b * HH + ch);
    f4 n1 = *(const f4*)(nx + (size_t)b * HH + ch + 4);
    f4 g0 = *(const f4*)(gg + ch), g1 = *(const f4*)(gg + ch + 4);
    f4 b0 = *(const f4*)(gb + ch), b1 = *(const f4*)(gb + ch + 4);
    float nv[8] = {n0.x,n0.y,n0.z,n0.w,n1.x,n1.y,n1.z,n1.w};
    float gv[8] = {g0.x,g0.y,g0.z,g0.w,g1.x,g1.y,g1.z,g1.w};
    float bv[8] = {b0.x,b0.y,b0.z,b0.w,b1.x,b1.y,b1.z,b1.w};
    bh8 o;
    #pragma unroll
    for (int e = 0; e < 8; e++) {
        float f = bf2f((unsigned short)v[e]);
        o[e] = (short)f2bf(fmaf(gv[e], f * nv[e], bv[e] + f));
    }
    *(bh8*)(h + flat) = o;
}

// ---------------- upsample scan
__global__ __launch_bounds__(256) void upscan_kernel(const int* __restrict__ text,
                                                     const int* __restrict__ audio,
                                                     int* __restrict__ pos,
                                                     int* __restrict__ lens) {
    int b = blockIdx.x, t = threadIdx.x;
    __shared__ int sc[256];
    int voff = 0, aoff = 0;
    for (int c = 0; c < LL / 256; c++) {
        int l = c * 256 + t;
        int am = audio[(size_t)b * LL + l];
        int tv = text[(size_t)b * LL + l];
        int valid = (am != 0 && tv != -1) ? 1 : 0;
        sc[t] = valid;
        __syncthreads();
        for (int off = 1; off < 256; off <<= 1) {
            int add = (t >= off) ? sc[t - off] : 0;
            __syncthreads();
            sc[t] += add;
            __syncthreads();
        }
        int incl = sc[t];
        if (valid) pos[(size_t)b * LL + voff + incl - 1] = l;
        voff += sc[255];
        __syncthreads();
        sc[t] = (am != 0) ? 1 : 0;
        __syncthreads();
        for (int off = 128; off > 0; off >>= 1) {
            if (t < off) sc[t] += sc[t + off];
            __syncthreads();
        }
        aoff += sc[0];
        __syncthreads();
    }
    if (t == 0) { lens[b * 2] = aoff; lens[b * 2 + 1] = voff; }
    for (int i = voff + t; i < LL; i += 256) pos[(size_t)b * LL + i] = LL - 1;
}

// ---------------- upsample gather
__global__ __launch_bounds__(256) void upgather_kernel(const float* __restrict__ x,
                                                       const int* __restrict__ pos,
                                                       const int* __restrict__ lens,
                                                       float* __restrict__ out) {
    int bid = blockIdx.x;            // b*L + p
    int b = bid >> 11;
    int p = bid & (LL - 1);
    int t = threadIdx.x;
    int alen = lens[b * 2], vlen = lens[b * 2 + 1];
    float v0 = 0.f, v1 = 0.f;
    if (p < alen && vlen > 0) {
        int vl = vlen < 1 ? 1 : vlen;
        int base = alen / vl, rem = alen % vl;
        int cut = (vl - rem) * base;
        int j;
        if (p < cut) j = p / (base < 1 ? 1 : base);
        else j = (vl - rem) + (p - cut) / (base + 1);
        j = j < 0 ? 0 : (j > LL - 1 ? LL - 1 : j);
        int s = pos[(size_t)b * LL + j];
        s = s < 0 ? 0 : (s > LL - 1 ? LL - 1 : s);
        const float* xr = x + ((size_t)b * LL + s) * DD;
        v0 = xr[t];
        v1 = xr[t + 256];
    }
    out[(size_t)bid * DD + t] = v0;
    out[(size_t)bid * DD + t + 256] = v1;
}

// ---------------- workspace layout (bytes)
#define OFF_FREQS  ((size_t)0)
#define OFF_X      (OFF_FREQS + (size_t)LL * DD * 4)          // 4 MB
#define OFF_XLN    (OFF_X + (size_t)MM * DD * 4)              // +64 MB
#define OFF_H      (OFF_XLN + (size_t)MM * DD * 2)            // +32 MB
#define OFF_W1T    (OFF_H + (size_t)MM * HH * 2)              // +64 MB
#define OFF_W2T    (OFF_W1T + (size_t)NL * HH * DD * 2)       // +4 MB
#define OFF_GXP    (OFF_W2T + (size_t)NL * DD * HH * 2)       // +4 MB
#define OFF_NX     (OFF_GXP + (size_t)8 * BB * HH * 4)        // +512 KB
#define OFF_POS    (OFF_NX + (size_t)BB * HH * 4)             // +64 KB
#define OFF_LENS   (OFF_POS + (size_t)BB * LL * 4)            // +128 KB

extern "C" void kernel_launch(void* const* d_in, const int* in_sizes, int n_in,
                              void* d_out, int out_size, void* d_ws, size_t ws_size,
                              hipStream_t stream) {
    const int*   text  = (const int*)d_in[0];
    const int*   audio = (const int*)d_in[1];
    const float* table = (const float*)d_in[3];
    const float* dw_w  = (const float*)d_in[4];
    const float* dw_b  = (const float*)d_in[5];
    const float* ln_g  = (const float*)d_in[6];
    const float* ln_b  = (const float*)d_in[7];
    const float* pw1_w = (const float*)d_in[8];
    const float* pw1_b = (const float*)d_in[9];
    const float* grn_g = (const float*)d_in[10];
    const float* grn_b = (const float*)d_in[11];
    const float* pw2_w = (const float*)d_in[12];
    const float* pw2_b = (const float*)d_in[13];
    float* out = (float*)d_out;

    char* ws = (char*)d_ws;
    float*          freqs = (float*)(ws + OFF_FREQS);
    float*          x     = (float*)(ws + OFF_X);
    unsigned short* xln   = (unsigned short*)(ws + OFF_XLN);
    unsigned short* h     = (unsigned short*)(ws + OFF_H);
    unsigned short* w1t   = (unsigned short*)(ws + OFF_W1T);
    unsigned short* w2t   = (unsigned short*)(ws + OFF_W2T);
    float*          gxp   = (float*)(ws + OFF_GXP);
    float*          nx    = (float*)(ws + OFF_NX);
    int*            pos   = (int*)(ws + OFF_POS);
    int*            lens  = (int*)(ws + OFF_LENS);

    freqs_kernel<<<LL, 256, 0, stream>>>(freqs);
    wtrans_kernel<<<dim3(HH / 64, DD / 64, NL), 256, 0, stream>>>(pw1_w, w1t, DD, HH);
    wtrans_kernel<<<dim3(DD / 64, HH / 64, NL), 256, 0, stream>>>(pw2_w, w2t, HH, DD);
    embed_kernel<<<MM, 128, 0, stream>>>(text, table, freqs, x);

    for (int layer = 0; layer < NL; layer++) {
        conv_ln_kernel<<<MM / (4 * CCH), 256, 0, stream>>>(x,
            dw_w + (size_t)layer * DD * 7, dw_b + (size_t)layer * DD,
            ln_g + (size_t)layer * DD, ln_b + (size_t)layer * DD, xln);

        gemm_bf16_kernel<DD, HH, 0><<<dim3(HH / 128, MM / 128), 256, 0, stream>>>(
            xln, w1t + (size_t)layer * HH * DD, pw1_b + (size_t)layer * HH,
            h, nullptr, nullptr);

        grn_sq_kernel<<<BB * (HH / 256) * (LL / 256), 256, 0, stream>>>(h, gxp);
        grn_stats_kernel<<<BB, 256, 0, stream>>>(gxp, nx);
        grn_apply_kernel<<<(int)(((size_t)MM * HH / 8) / 256), 256, 0, stream>>>(
            h, nx, grn_g + (size_t)layer * HH, grn_b + (size_t)layer * HH);

        gemm_bf16_kernel<HH, DD, 1><<<dim3(DD / 128, MM / 128), 256, 0, stream>>>(
            h, w2t + (size_t)layer * DD * HH, pw2_b + (size_t)layer * DD,
            nullptr, x, text);
    }

    upscan_kernel<<<BB, 256, 0, stream>>>(text, audio, pos, lens);
    upgather_kernel<<<MM, 256, 0, stream>>>(x, pos, lens, out);
}